// Round 11
// baseline (514.068 us; speedup 1.0000x reference)
//
#include <hip/hip_runtime.h>

// ============================================================================
// VQ-VAE forward on MI355X (gfx950)
// Numerics: encoder + VQ-distance as split-f16 3-pass GEMMs
//           (Ah*Bh + Ah*Bl + Al*Bh, ~2^-22 rel err) so the codebook argmin
//           matches the fp64/np reference; decoder plain f16; fp32 accum.
// enc0/enc1: vq_gemmS — 256x256, BK=32, 4-panel double-buffer, operand reuse,
//   TIGHT 5-phase schedule (r9-verified: 170us, MfmaUtil 56.3%, 1212 TF),
//   counted vmcnt(8), K-split slabs + vq_ksum epilogue.
//   [r10 3-phase variant regressed 52.8% -> reverted; r7 loose regressed 47%]
// dec1: 256x128 merged 2-phase; dec2: 256x256 8-phase (both verified).
// Fused small kernels: vq_prep, vq_tsplit_all, vq_gather_loss (r9-verified).
// ============================================================================

typedef _Float16 f16;
typedef _Float16 f16x8 __attribute__((ext_vector_type(8)));
typedef _Float16 f16x4 __attribute__((ext_vector_type(4)));
typedef float    f32x4 __attribute__((ext_vector_type(4)));

// ---- async global->LDS (width 16) ------------------------------------------
typedef const unsigned int __attribute__((address_space(1)))* gp1_t;
typedef unsigned int __attribute__((address_space(3)))*       lp3_t;

__device__ __forceinline__ void gl_lds16(const void* g, void* l) {
  __builtin_amdgcn_global_load_lds((gp1_t)g, (lp3_t)l, 16, 0, 0);
}

// ---- problem constants -----------------------------------------------------
#define BATCH 32
#define CDIM  128
#define WDIM  4096
#define LDIM  512
#define KCB   512
#define DCB   128

// scales (powers of two, exact)
#define SX    128.0f
#define SW    256.0f
#define SA    256.0f
#define SCB   4096.0f
#define SQ    4096.0f

#define G8_BAR() do { asm volatile("" ::: "memory"); \
  __builtin_amdgcn_s_barrier(); asm volatile("" ::: "memory"); } while (0)
#define G8_LGKM0() do { asm volatile("s_waitcnt lgkmcnt(0)" ::: "memory"); \
  __builtin_amdgcn_sched_barrier(0); } while (0)
#define G8_PRIO1() __builtin_amdgcn_s_setprio(1)
#define G8_PRIO0() __builtin_amdgcn_s_setprio(0)

// ============================================================================
// vq_gemmS: split GEMM with operand reuse.  C = Ah*Bh^T + Ah*Bl^T + Al*Bh^T
// 256x256 tile, 8 waves (2x4), wave tile 128x64, BK=32.
// Per buffer (64KB): [Ah 16K][Al 16K][Bh 16K][Bl 16K]; 2 buffers = 128KB.
// Swizzle (64B rows): 16B chunk c stored at c ^ ((row>>1)&3); read applies
// same XOR -> 64-lane ds_read_b128 covers all 8 slots/128B window (2/bank).
// Per kk-tile: 5 phases {16,16,16,16,32} MFMA; stages BH@P1 BL@P2 AH@P3 AL@P4
// (each >=1 barrier after that panel's last read); gate vmcnt(8).
// Writes raw f32 partial to slab blockIdx.y of Co (K-split; vq_ksum reduces).
// ============================================================================

#define GS_STAGE(src, row0, kk, off) \
  _Pragma("unroll") \
  for (int j_ = 0; j_ < 2; ++j_) { \
    const int p_ = j_ * 8192 + tid * 16; \
    const int r_ = p_ >> 6; \
    const int c_ = (p_ >> 4) & 3; \
    gl_lds16((src) + (size_t)((row0) + r_) * K + (kk) + ((c_ ^ ((r_ >> 1) & 3)) << 3), \
             smem + (off) + p_); \
  }

#define GS_ST(tt, pb, SRC, row0, poff) do { \
  const int tc_ = (tt) < NTloc ? (tt) : NTloc - 1; \
  const int kk_ = (t0 + tc_) << 5; \
  GS_STAGE(SRC, row0, kk_, (pb) * 65536 + (poff)) } while (0)

#define GS_READ_A(pb, HL, half, dst) \
  _Pragma("unroll") \
  for (int m_ = 0; m_ < 4; ++m_) { \
    const int r_ = wr * 128 + ((half) * 4 + m_) * 16 + fr; \
    dst[m_] = *(const f16x8*)(smem + (pb) * 65536 + (HL) * 16384 + r_ * 64 + swz16); \
  }

#define GS_READ_B(pb, HL, brr) \
  _Pragma("unroll") \
  for (int n_ = 0; n_ < 4; ++n_) { \
    const int r_ = wc * 64 + n_ * 16 + fr; \
    brr[n_] = *(const f16x8*)(smem + (pb) * 65536 + 32768 + (HL) * 16384 + r_ * 64 + swz16); \
  }

#define GS_MFMA(aarr, half, brr) \
  _Pragma("unroll") \
  for (int m_ = 0; m_ < 4; ++m_) \
  _Pragma("unroll") \
  for (int n_ = 0; n_ < 4; ++n_) \
    acc[(half) * 4 + m_][n_] = __builtin_amdgcn_mfma_f32_16x16x32_f16( \
        aarr[m_], brr[n_], acc[(half) * 4 + m_][n_], 0, 0, 0);

__global__ __launch_bounds__(512, 2)
void vq_gemmS(const f16* __restrict__ Ah, const f16* __restrict__ Al,
              const f16* __restrict__ Bh, const f16* __restrict__ Bl,
              float* __restrict__ Co, int M, int N, int K, int NTloc)
{
  __shared__ __align__(16) char smem[131072];

  const int tid = threadIdx.x;
  const int lane = tid & 63;
  const int w = tid >> 6;
  const int wr = w >> 2, wc = w & 3;       // 2x4 wave grid, 128x64 per wave
  const int fr = lane & 15, hq = lane >> 4;
  const int swz16 = (hq ^ ((fr >> 1) & 3)) << 4;

  const int nbx = N / 256;
  const int cpx = (int)gridDim.x >> 3;     // gridDim.x % 8 == 0
  const int swzb = ((int)blockIdx.x & 7) * cpx + ((int)blockIdx.x >> 3);
  const int bx = swzb % nbx, by = swzb / nbx;
  const int m0 = by * 256, n0 = bx * 256;
  const int t0 = (int)blockIdx.y * NTloc;  // kk-tile (32-wide) offset

  f32x4 acc[8][4] = {};
  f16x8 ah0[4], ah1[4], al0[4], al1[4], bh[4], bl[4];

  // ---- prologue: tiles 0 and 1 (8 loads each, FIFO per tile) ----
  GS_ST(0, 0, Bh, n0, 32768); GS_ST(0, 0, Bl, n0, 49152);
  GS_ST(0, 0, Ah, m0, 0);     GS_ST(0, 0, Al, m0, 16384);
  GS_ST(1, 1, Bh, n0, 32768); GS_ST(1, 1, Bl, n0, 49152);
  GS_ST(1, 1, Ah, m0, 0);     GS_ST(1, 1, Al, m0, 16384);

  int pb = 0;
  for (int t = 0; t < NTloc; ++t) {
    asm volatile("s_waitcnt vmcnt(8)" ::: "memory");   // tile t landed; t+1 in flight
    G8_BAR();
    // P0: reads ah[0..3], bh
    GS_READ_A(pb, 0, 0, ah0) GS_READ_B(pb, 0, bh)
    G8_BAR(); G8_LGKM0();
    G8_PRIO1(); GS_MFMA(ah0, 0, bh) G8_PRIO0();
    G8_BAR();
    // P1: reads al[0..3], bl; stage BH(t+2) [Bh reads done P0]
    GS_READ_A(pb, 1, 0, al0) GS_READ_B(pb, 1, bl)
    GS_ST(t + 2, pb, Bh, n0, 32768);
    G8_BAR(); G8_LGKM0();
    G8_PRIO1(); GS_MFMA(ah0, 0, bl) G8_PRIO0();
    G8_BAR();
    // P2: reads ah[4..7]; stage BL(t+2) [Bl reads done P1]
    GS_READ_A(pb, 0, 1, ah1)
    GS_ST(t + 2, pb, Bl, n0, 49152);
    G8_BAR(); G8_LGKM0();
    G8_PRIO1(); GS_MFMA(al0, 0, bh) G8_PRIO0();
    G8_BAR();
    // P3: reads al[4..7]; stage AH(t+2) [Ah reads done P2]
    GS_READ_A(pb, 1, 1, al1)
    GS_ST(t + 2, pb, Ah, m0, 0);
    G8_BAR(); G8_LGKM0();
    G8_PRIO1(); GS_MFMA(ah1, 1, bh) G8_PRIO0();
    G8_BAR();
    // P4: stage AL(t+2) [Al reads done P3]; 32 MFMA (all regs complete)
    GS_ST(t + 2, pb, Al, m0, 16384);
    G8_PRIO1(); GS_MFMA(ah1, 1, bl) GS_MFMA(al1, 1, bh) G8_PRIO0();
    pb ^= 1;
    // closing gate is next iteration's head
  }

  // ---- epilogue: raw f32 partials to slab blockIdx.y ----
  float* Pslab = Co + (size_t)blockIdx.y * M * N;
  const int r4 = hq * 4;
#pragma unroll
  for (int mi = 0; mi < 8; ++mi) {
#pragma unroll
    for (int ni = 0; ni < 4; ++ni) {
      const int col = n0 + wc * 64 + ni * 16 + fr;
#pragma unroll
      for (int j = 0; j < 4; ++j) {
        const int row = m0 + wr * 128 + mi * 16 + r4 + j;
        Pslab[(size_t)row * N + col] = acc[mi][ni][j];
      }
    }
  }
}

// ============================================================================
// 8-wave GEMM (decoder): C[M,N] = A[M,K] @ B^T[N,K]  (non-split paths)
// ============================================================================

#define G8_SRC(t, As, Bs, kk) \
  const f16 *As, *Bs; int kk; \
  { int ts_ = (t) < NTloc ? (t) : NTloc - 1; int kg_ = (t0 + ts_) << 6; \
    if (SPLIT) { int sg_ = (kg_ >= 2 * K) ? 2 : ((kg_ >= K) ? 1 : 0); \
      kk = kg_ - sg_ * K; As = (sg_ == 2) ? Al : Ah; Bs = (sg_ == 1) ? Bl : Bh; } \
    else { As = Ah; Bs = Bh; kk = kg_; } }

#define G8_STAGE(src, row0, kk, off) \
  _Pragma("unroll") \
  for (int j_ = 0; j_ < 2; ++j_) { \
    const int p_ = j_ * 8192 + tid * 16; \
    const int r_ = p_ >> 7; \
    const int c_ = (p_ >> 4) & 7; \
    gl_lds16((src) + (size_t)((row0) + r_) * K + (kk) + ((c_ ^ (r_ & 7)) << 3), \
             smem + (off) + p_); \
  }

#define G8_STAGE_A(t, u) do { G8_SRC(t, As_, Bs_, kk_) \
  G8_STAGE(As_, m0 + (u) * 128, kk_, ((t) & 1) * ASZ + (u) * 16384) } while (0)
#define G8_STAGE_B(t, u) do { G8_SRC(t, As_, Bs_, kk_) \
  G8_STAGE(Bs_, n0 + (u) * 128, kk_, BBASE + ((t) & 1) * BSZ + (u) * 16384) } while (0)

#define G8_READ_A(buf, mh) \
  _Pragma("unroll") \
  for (int m_ = 0; m_ < MR2; ++m_) { \
    const int r_ = wr * (MR * 16) + ((mh) * MR2 + m_) * 16 + fr; \
    _Pragma("unroll") \
    for (int ks_ = 0; ks_ < 2; ++ks_) \
      ar[m_][ks_] = *(const f16x8*)(smem + (buf) * ASZ + r_ * 128 + \
                                    ((((ks_ << 2) + hq) ^ (r_ & 7)) << 4)); \
  }

#define G8_READ_B(buf, nh, br) \
  _Pragma("unroll") \
  for (int n_ = 0; n_ < 2; ++n_) { \
    const int r_ = wc * 64 + ((nh) * 2 + n_) * 16 + fr; \
    _Pragma("unroll") \
    for (int ks_ = 0; ks_ < 2; ++ks_) \
      br[n_][ks_] = *(const f16x8*)(smem + BBASE + (buf) * BSZ + r_ * 128 + \
                                    ((((ks_ << 2) + hq) ^ (r_ & 7)) << 4)); \
  }

#define G8_MFMA(mh, nh, br) \
  _Pragma("unroll") \
  for (int m_ = 0; m_ < MR2; ++m_) \
  _Pragma("unroll") \
  for (int n_ = 0; n_ < 2; ++n_) \
  _Pragma("unroll") \
  for (int ks_ = 0; ks_ < 2; ++ks_) \
    acc[(mh) * MR2 + m_][(nh) * 2 + n_] = __builtin_amdgcn_mfma_f32_16x16x32_f16( \
        ar[m_][ks_], br[n_][ks_], acc[(mh) * MR2 + m_][(nh) * 2 + n_], 0, 0, 0);

#define G8_VMGATE() do { \
  if constexpr (BUNITS == 2) asm volatile("s_waitcnt vmcnt(4)" ::: "memory"); \
  else                       asm volatile("s_waitcnt vmcnt(2)" ::: "memory"); } while (0)

template<int SPLIT, int EPI, int WM, int WN, int MR>
__global__ __launch_bounds__(512, 2)
void vq_gemm8(const f16* __restrict__ Ah, const f16* __restrict__ Al,
              const f16* __restrict__ Bh, const f16* __restrict__ Bl,
              const float* __restrict__ bias,
              void* __restrict__ Co, void* __restrict__ Co2,
              int M, int N, int K, int NTloc, float unscale, float outscale)
{
  constexpr int MR2 = MR / 2;
  constexpr int GBM = WM * MR * 16;      // 256
  constexpr int GBN = WN * 64;           // 128 or 256
  constexpr int BUNITS = GBN / 128;      // 1 or 2
  constexpr int ASZ = GBM * 128;         // bytes per A buffer (32KB)
  constexpr int BSZ = GBN * 128;         // bytes per B buffer
  constexpr int BBASE = 2 * ASZ;
  constexpr int LDSZ = 2 * ASZ + 2 * BSZ;  // 96KB / 128KB

  __shared__ __align__(16) char smem[LDSZ];

  const int tid = threadIdx.x;
  const int lane = tid & 63;
  const int w = tid >> 6;
  const int wr = w / WN, wc = w % WN;
  const int fr = lane & 15, hq = lane >> 4;

  const int nbx = N / GBN;
  const int cpx = (int)gridDim.x >> 3;   // gridDim.x % 8 == 0 at all call sites
  const int swz = ((int)blockIdx.x & 7) * cpx + ((int)blockIdx.x >> 3);
  const int bx = swz % nbx, by = swz / nbx;
  const int m0 = by * GBM, n0 = bx * GBN;
  const int t0 = (int)blockIdx.y * NTloc;

  const int NI = NTloc >> 1;

  f32x4 acc[MR][4] = {};
  f16x8 ar[MR2][2], br0[2][2], br1[2][2];

  // ---- prologue: tile0 complete + tile1 B unit(s) (order drives vmcnt) ----
  G8_STAGE_B(0, 0); if constexpr (BUNITS == 2) G8_STAGE_B(0, 1);
  G8_STAGE_A(0, 0); G8_STAGE_A(0, 1);
  G8_STAGE_B(1, 0); if constexpr (BUNITS == 2) G8_STAGE_B(1, 1);

  for (int i = 0; i < NI; ++i) {
    const int to = 2 * i + 1, te = 2 * i + 2, to2 = 2 * i + 3;
    if constexpr (BUNITS == 1) {
      // ---- merged: 2 phases per K-tile, 16 MFMA per phase (round-3) ----
      G8_VMGATE(); G8_BAR();
      G8_READ_A(0, 0) G8_READ_B(0, 0, br0) G8_READ_B(0, 1, br1)
      G8_STAGE_A(to, 0); G8_STAGE_A(to, 1);
      G8_BAR(); G8_LGKM0();
      G8_PRIO1(); G8_MFMA(0, 0, br0) G8_MFMA(0, 1, br1) G8_PRIO0();
      G8_BAR();
      G8_READ_A(0, 1)
      G8_STAGE_B(te, 0);
      G8_BAR(); G8_LGKM0();
      G8_PRIO1(); G8_MFMA(1, 0, br0) G8_MFMA(1, 1, br1) G8_PRIO0();
      G8_VMGATE(); G8_BAR();
      G8_READ_A(1, 0) G8_READ_B(1, 0, br0) G8_READ_B(1, 1, br1)
      G8_STAGE_A(te, 0); G8_STAGE_A(te, 1);
      G8_BAR(); G8_LGKM0();
      G8_PRIO1(); G8_MFMA(0, 0, br0) G8_MFMA(0, 1, br1) G8_PRIO0();
      G8_BAR();
      G8_READ_A(1, 1)
      G8_STAGE_B(to2, 0);
      G8_BAR(); G8_LGKM0();
      G8_PRIO1(); G8_MFMA(1, 0, br0) G8_MFMA(1, 1, br1) G8_PRIO0();
    } else {
      // ---- 256x256: 8-phase m201 shape, 16 MFMA per phase ----
      G8_VMGATE(); G8_BAR();
      G8_READ_A(0, 0) G8_READ_B(0, 0, br0)
      G8_STAGE_A(to, 0);
      G8_BAR(); G8_LGKM0(); G8_PRIO1(); G8_MFMA(0, 0, br0) G8_PRIO0();
      G8_BAR();
      G8_READ_B(0, 1, br1)
      G8_STAGE_A(to, 1);
      G8_BAR(); G8_LGKM0(); G8_PRIO1(); G8_MFMA(0, 1, br1) G8_PRIO0();
      G8_BAR();
      G8_READ_A(0, 1)
      G8_STAGE_B(te, 0);
      G8_BAR(); G8_LGKM0(); G8_PRIO1(); G8_MFMA(1, 0, br0) G8_PRIO0();
      G8_BAR();
      G8_STAGE_B(te, 1);
      G8_BAR(); G8_PRIO1(); G8_MFMA(1, 1, br1) G8_PRIO0();
      G8_VMGATE(); G8_BAR();
      G8_READ_A(1, 0) G8_READ_B(1, 0, br0)
      G8_STAGE_A(te, 0);
      G8_BAR(); G8_LGKM0(); G8_PRIO1(); G8_MFMA(0, 0, br0) G8_PRIO0();
      G8_BAR();
      G8_READ_B(1, 1, br1)
      G8_STAGE_A(te, 1);
      G8_BAR(); G8_LGKM0(); G8_PRIO1(); G8_MFMA(0, 1, br1) G8_PRIO0();
      G8_BAR();
      G8_READ_A(1, 1)
      G8_STAGE_B(to2, 0);
      G8_BAR(); G8_LGKM0(); G8_PRIO1(); G8_MFMA(1, 0, br0) G8_PRIO0();
      G8_BAR();
      G8_STAGE_B(to2, 1);
      G8_BAR(); G8_PRIO1(); G8_MFMA(1, 1, br1) G8_PRIO0();
    }
  }

  // ---- epilogue ----
  const int r4 = hq * 4;
#pragma unroll
  for (int mi = 0; mi < MR; ++mi) {
#pragma unroll
    for (int ni = 0; ni < 4; ++ni) {
      const int col = n0 + wc * 64 + ni * 16 + fr;
      const float bv = (EPI == 0) ? 0.f : bias[col];
#pragma unroll
      for (int j = 0; j < 4; ++j) {
        const int row = m0 + wr * (MR * 16) + mi * 16 + r4 + j;
        const size_t idx = (size_t)row * N + col;
        float y = acc[mi][ni][j] * unscale;
        if (EPI != 0) y += bv;
        if (EPI == 1 || EPI == 2) y = fmaxf(y, 0.f);
        if (EPI == 0 || EPI == 3) ((float*)Co)[idx] = y;
        else {
          const float ys = y * outscale;
          const f16 hv = (f16)ys;
          ((f16*)Co)[idx] = hv;
          if (EPI == 1) ((f16*)Co2)[idx] = (f16)(ys - (float)hv);
        }
      }
    }
  }
}

// ---- K-split reduction epilogue: sum NS slabs + bias + relu + hi/lo split --
template<int NS>
__global__ void vq_ksum(const float* __restrict__ P, const float* __restrict__ bias,
                        f16* __restrict__ Oh, f16* __restrict__ Ol,
                        int MN, int N, float unscale, float outscale)
{
  const int i4 = (blockIdx.x * 256 + threadIdx.x) * 4;
  if (i4 >= MN) return;
  float4 s = ((const float4*)P)[i4 >> 2];
#pragma unroll
  for (int sl = 1; sl < NS; ++sl) {
    const float4 v = ((const float4*)(P + (size_t)sl * MN))[i4 >> 2];
    s.x += v.x; s.y += v.y; s.z += v.z; s.w += v.w;
  }
  const int col = i4 % N;   // N % 4 == 0, i4..i4+3 share the row
  f16x4 h, l;
#pragma unroll
  for (int j = 0; j < 4; ++j) {
    float y = (&s.x)[j] * unscale + bias[col + j];
    y = fmaxf(y, 0.f) * outscale;
    const f16 hv = (f16)y;
    h[j] = hv;
    l[j] = (f16)(y - (float)hv);
  }
  *(f16x4*)&Oh[i4] = h;
  *(f16x4*)&Ol[i4] = l;
}

// ============================================================================
// 2-phase 128^2 GEMM (verified round-1) for the small/odd-shaped GEMMs
// ============================================================================
#define BM 128
#define BN 128
#define BK 32

template<int SPLIT, int EPI>
__global__ __launch_bounds__(256, 2)
void vq_gemm(const f16* __restrict__ Ah, const f16* __restrict__ Al,
             const f16* __restrict__ Bh, const f16* __restrict__ Bl,
             const float* __restrict__ bias,
             void* __restrict__ Co, void* __restrict__ Co2,
             int M, int N, int K, float unscale, float outscale)
{
  __shared__ __align__(16) f16 sAh[BM * BK];
  __shared__ __align__(16) f16 sBh[BN * BK];
  __shared__ __align__(16) f16 sAl[SPLIT ? BM * BK : 8];
  __shared__ __align__(16) f16 sBl[SPLIT ? BN * BK : 8];

  const int tid  = threadIdx.x;
  const int lane = tid & 63;
  const int w    = tid >> 6;
  const int nb   = N / BN;
  const int bx   = blockIdx.x % nb;
  const int by   = blockIdx.x / nb;
  const int m0   = by * BM, n0 = bx * BN;
  const int wr   = w >> 1, wc = w & 1;
  const int fr   = lane & 15;
  const int ko   = (lane >> 4) * 8;

  f32x4 acc[4][4] = {};

  const int srow = lane >> 2;
  const int skb  = (lane & 3) * 8;

  for (int k0 = 0; k0 < K; k0 += BK) {
#pragma unroll
    for (int i = 0; i < 2; ++i) {
      const int c  = w * 2 + i;
      const size_t ga = (size_t)(m0 + c * 16 + srow) * K + k0 + skb;
      const size_t gb = (size_t)(n0 + c * 16 + srow) * K + k0 + skb;
      gl_lds16(Ah + ga, &sAh[c * 512]);
      gl_lds16(Bh + gb, &sBh[c * 512]);
      if (SPLIT) {
        gl_lds16(Al + ga, &sAl[c * 512]);
        gl_lds16(Bl + gb, &sBl[c * 512]);
      }
    }
    __syncthreads();

    f16x8 ah[4], bh[4], al[4], bl[4];
#pragma unroll
    for (int mi = 0; mi < 4; ++mi) {
      const int r = (wr * 64 + mi * 16 + fr) * BK + ko;
      ah[mi] = *(const f16x8*)&sAh[r];
      if (SPLIT) al[mi] = *(const f16x8*)&sAl[r];
    }
#pragma unroll
    for (int ni = 0; ni < 4; ++ni) {
      const int r = (wc * 64 + ni * 16 + fr) * BK + ko;
      bh[ni] = *(const f16x8*)&sBh[r];
      if (SPLIT) bl[ni] = *(const f16x8*)&sBl[r];
    }
#pragma unroll
    for (int mi = 0; mi < 4; ++mi)
#pragma unroll
      for (int ni = 0; ni < 4; ++ni) {
        acc[mi][ni] = __builtin_amdgcn_mfma_f32_16x16x32_f16(ah[mi], bh[ni], acc[mi][ni], 0, 0, 0);
        if (SPLIT) {
          acc[mi][ni] = __builtin_amdgcn_mfma_f32_16x16x32_f16(ah[mi], bl[ni], acc[mi][ni], 0, 0, 0);
          acc[mi][ni] = __builtin_amdgcn_mfma_f32_16x16x32_f16(al[mi], bh[ni], acc[mi][ni], 0, 0, 0);
        }
      }
    __syncthreads();
  }

  const int r4 = (lane >> 4) * 4;
#pragma unroll
  for (int mi = 0; mi < 4; ++mi) {
#pragma unroll
    for (int ni = 0; ni < 4; ++ni) {
      const int col = n0 + wc * 64 + ni * 16 + fr;
      const float bv = (EPI == 0) ? 0.0f : bias[col];
#pragma unroll
      for (int j = 0; j < 4; ++j) {
        const int row = m0 + wr * 64 + mi * 16 + r4 + j;
        float y = acc[mi][ni][j] * unscale;
        if (EPI != 0) y += bv;
        if (EPI == 1 || EPI == 2) y = fmaxf(y, 0.0f);
        const size_t idx = (size_t)row * N + col;
        if (EPI == 0 || EPI == 3) {
          ((float*)Co)[idx] = y;
        } else {
          const float ys = y * outscale;
          const f16 hv = (f16)ys;
          ((f16*)Co)[idx] = hv;
          if (EPI == 1) ((f16*)Co2)[idx] = (f16)(ys - (float)hv);
        }
      }
    }
  }
}

// ---- fused prep: x-split (+exact out1 copy) | cb-split | cbnorm ------------
__global__ void vq_prep(const float* __restrict__ x, f16* __restrict__ XH,
                        f16* __restrict__ XL, float* __restrict__ raw,
                        const float* __restrict__ cb, f16* __restrict__ CBH,
                        f16* __restrict__ CBL, float* __restrict__ cbn)
{
  const int b = blockIdx.x;
  if (b < 16384) {                     // x: 16384 blocks x 256 thr x 4 elems
    const int i = b * 256 + threadIdx.x;
    const float4 v = ((const float4*)x)[i];
    ((float4*)raw)[i] = v;             // output 1: exact copy
    f16x4 h, l;
#pragma unroll
    for (int j = 0; j < 4; ++j) {
      const float s = (&v.x)[j] * SX;
      const f16 hh = (f16)s;
      h[j] = hh;
      l[j] = (f16)(s - (float)hh);
    }
    *(f16x4*)&XH[i * 4] = h;
    *(f16x4*)&XL[i * 4] = l;
  } else if (b < 16448) {              // cb split: 64 blocks (512*128/4/256)
    const int i = (b - 16384) * 256 + threadIdx.x;
    const float4 v = ((const float4*)cb)[i];
    f16x4 h, l;
#pragma unroll
    for (int j = 0; j < 4; ++j) {
      const float s = (&v.x)[j] * SCB;
      const f16 hh = (f16)s;
      h[j] = hh;
      l[j] = (f16)(s - (float)hh);
    }
    *(f16x4*)&CBH[i * 4] = h;
    *(f16x4*)&CBL[i * 4] = l;
  } else {                             // cbnorm: 2 blocks
    const int k = (b - 16448) * 256 + threadIdx.x;
    if (k < KCB) {
      float s = 0.f;
      for (int c = 0; c < DCB; ++c) { const float v = cb[k * DCB + c]; s += v * v; }
      cbn[k] = s;
    }
  }
}

// ---- fused weight transpose+split: all 6 weights in one launch -------------
__global__ void vq_tsplit_all(
    const float* __restrict__ ew0, f16* __restrict__ EW0H, f16* __restrict__ EW0L,
    const float* __restrict__ ew1, f16* __restrict__ EW1H, f16* __restrict__ EW1L,
    const float* __restrict__ ew2, f16* __restrict__ EW2H, f16* __restrict__ EW2L,
    const float* __restrict__ dw0, f16* __restrict__ DW0,
    const float* __restrict__ dw1, f16* __restrict__ DW1,
    const float* __restrict__ dw2, f16* __restrict__ DW2)
{
  __shared__ float t[32][33];
  int b = blockIdx.x;
  const float* W; f16* Th; f16* Tl; int K, N, gx, wl;
  if (b < 8192)        { W = ew0; Th = EW0H; Tl = EW0L; K = 4096; N = 2048; gx = 64;  wl = 1; }
  else if (b < 10240)  { b -= 8192;  W = ew1; Th = EW1H; Tl = EW1L; K = 2048; N = 1024; gx = 32;  wl = 1; }
  else if (b < 10752)  { b -= 10240; W = ew2; Th = EW2H; Tl = EW2L; K = 1024; N = 512;  gx = 16;  wl = 1; }
  else if (b < 11264)  { b -= 10752; W = dw0; Th = DW0;  Tl = nullptr; K = 512;  N = 1024; gx = 32;  wl = 0; }
  else if (b < 13312)  { b -= 11264; W = dw1; Th = DW1;  Tl = nullptr; K = 1024; N = 2048; gx = 64;  wl = 0; }
  else                 { b -= 13312; W = dw2; Th = DW2;  Tl = nullptr; K = 2048; N = 4096; gx = 128; wl = 0; }
  const int n0 = (b % gx) * 32, k0 = (b / gx) * 32;
  const int tx = threadIdx.x & 31, ty = threadIdx.x >> 5;
#pragma unroll
  for (int i = 0; i < 4; ++i)
    t[ty + i * 8][tx] = W[(size_t)(k0 + ty + i * 8) * N + n0 + tx];
  __syncthreads();
#pragma unroll
  for (int i = 0; i < 4; ++i) {
    const int n = n0 + ty + i * 8;
    const float v = t[tx][ty + i * 8] * SW;
    const f16 hv = (f16)v;
    Th[(size_t)n * K + k0 + tx] = hv;
    if (wl) Tl[(size_t)n * K + k0 + tx] = (f16)(v - (float)hv);
  }
}

// ---- transpose H2[(b,c),l] -> flat[(b,l),c] for hi/lo pair -----------------
__global__ void vq_tpose(const f16* __restrict__ Hh, const f16* __restrict__ Hl,
                         f16* __restrict__ Fh, f16* __restrict__ Fl)
{
  __shared__ f16 th[32][33];
  __shared__ f16 tl[32][33];
  const int bidx = blockIdx.x;
  const int b = bidx >> 6, rem = bidx & 63;
  const int l0 = (rem >> 2) * 32, c0 = (rem & 3) * 32;
  const int tx = threadIdx.x & 31, ty = threadIdx.x >> 5;
  const size_t hbase = (size_t)b * CDIM * LDIM;
#pragma unroll
  for (int i = 0; i < 4; ++i) {
    const int c = c0 + ty + i * 8;
    th[ty + i * 8][tx] = Hh[hbase + (size_t)c * LDIM + l0 + tx];
    tl[ty + i * 8][tx] = Hl[hbase + (size_t)c * LDIM + l0 + tx];
  }
  __syncthreads();
  const size_t fbase = (size_t)b * LDIM * DCB;
#pragma unroll
  for (int i = 0; i < 4; ++i) {
    const int l = l0 + ty + i * 8;
    Fh[fbase + (size_t)l * DCB + c0 + tx] = th[tx][ty + i * 8];
    Fl[fbase + (size_t)l * DCB + c0 + tx] = tl[tx][ty + i * 8];
  }
}

// ---- argmin over codes: d_k = ||c_k||^2 - 2*G[row,k]; first-min semantics --
__global__ void vq_argmin(const float* __restrict__ G, const float* __restrict__ cbn,
                          int* __restrict__ inds)
{
  const int row = blockIdx.x;
  const int lane = threadIdx.x;          // blockDim = 64
  const float* g = G + (size_t)row * KCB;
  float best = 1e30f; int bi = 0;
#pragma unroll
  for (int j = 0; j < 8; ++j) {
    const int k = j * 64 + lane;
    const float d = cbn[k] - 2.0f * g[k];
    if (d < best) { best = d; bi = k; }
  }
  for (int off = 32; off; off >>= 1) {
    const float ov = __shfl_xor(best, off);
    const int oi = __shfl_xor(bi, off);
    if (ov < best || (ov == best && oi < bi)) { best = ov; bi = oi; }
  }
  if (lane == 0) inds[row] = bi;
}

// ---- fused gather + loss (both depend only on inds) ------------------------
// gather: 8192 blocks (BATCH*CDIM*LDIM/256 = 2097152/256); loss: 256 blocks.
__global__ void vq_gather_loss(const float* __restrict__ cb, const int* __restrict__ inds,
                               f16* __restrict__ z0,
                               const f16* __restrict__ Fh, const f16* __restrict__ Fl,
                               float* __restrict__ partials)
{
  if (blockIdx.x < 8192) {
    // gather: z0[(b,c),l] = cb[ind[b,l]][c] * SQ
    const int t = blockIdx.x * 256 + threadIdx.x;   // t < 2097152
    const int l = t & 511, c = (t >> 9) & 127, b = t >> 16;  // b < 32
    const int ind = inds[b * LDIM + l];
    z0[t] = (f16)(cb[ind * DCB + c] * SQ);
  } else {
    // loss partials: 256 virtual blocks
    const int bid = blockIdx.x - 8192;
    const int gw = (bid * 256 + threadIdx.x) >> 6;
    const int lane = threadIdx.x & 63;
    float s = 0.f;
    for (int r = gw; r < BATCH * LDIM; r += 1024) {
      const int ind = inds[r];
      const f16* fh = Fh + (size_t)r * DCB;
      const f16* fl = Fl + (size_t)r * DCB;
      const float* q = cb + (size_t)ind * DCB;
#pragma unroll
      for (int j = 0; j < 2; ++j) {
        const int c = j * 64 + lane;
        const float lat = ((float)fh[c] + (float)fl[c]) * (1.0f / SA);
        const float d = q[c] - lat;
        s += d * d;
      }
    }
    for (int off = 32; off; off >>= 1) s += __shfl_xor(s, off);
    __shared__ float wsum[4];
    if (lane == 0) wsum[threadIdx.x >> 6] = s;
    __syncthreads();
    if (threadIdx.x == 0) partials[bid] = wsum[0] + wsum[1] + wsum[2] + wsum[3];
  }
}

__global__ void vq_loss_final(const float* __restrict__ partials, float* __restrict__ out)
{
  float s = partials[threadIdx.x];
  for (int off = 32; off; off >>= 1) s += __shfl_xor(s, off);
  __shared__ float wsum[4];
  if ((threadIdx.x & 63) == 0) wsum[threadIdx.x >> 6] = s;
  __syncthreads();
  if (threadIdx.x == 0)
    out[0] = (wsum[0] + wsum[1] + wsum[2] + wsum[3]) * (1.25f / (float)(BATCH * LDIM * DCB));
}

// ============================================================================
// launch
// ============================================================================
extern "C" void kernel_launch(void* const* d_in, const int* in_sizes, int n_in,
                              void* d_out, int out_size, void* d_ws, size_t ws_size,
                              hipStream_t stream)
{
  const float* x   = (const float*)d_in[0];
  const float* ew0 = (const float*)d_in[1];
  const float* eb0 = (const float*)d_in[2];
  const float* ew1 = (const float*)d_in[3];
  const float* eb1 = (const float*)d_in[4];
  const float* ew2 = (const float*)d_in[5];
  const float* eb2 = (const float*)d_in[6];
  const float* cb  = (const float*)d_in[7];
  const float* dw0 = (const float*)d_in[8];
  const float* db0 = (const float*)d_in[9];
  const float* dw1 = (const float*)d_in[10];
  const float* db1 = (const float*)d_in[11];
  const float* dw2 = (const float*)d_in[12];
  const float* db2 = (const float*)d_in[13];
  float* out = (float*)d_out;

  constexpr size_t N_X  = 4096ull * 4096;
  constexpr size_t N_E0 = 4096ull * 2048, N_E1 = 2048ull * 1024, N_E2 = 1024ull * 512;
  constexpr size_t N_CB = 512ull * 128;
  constexpr size_t N_D0 = 512ull * 1024, N_D1 = 1024ull * 2048, N_D2 = 2048ull * 4096;
  constexpr size_t N_H0 = 4096ull * 2048, N_H1 = 4096ull * 1024, N_H2 = 4096ull * 512;
  constexpr size_t N_FL = 16384ull * 128;
  constexpr size_t N_Z1 = 4096ull * 1024;

  constexpr size_t O_EW0H = 0;
  constexpr size_t O_EW0L = O_EW0H + N_E0 * 2;
  constexpr size_t O_EW1H = O_EW0L + N_E0 * 2;
  constexpr size_t O_EW1L = O_EW1H + N_E1 * 2;
  constexpr size_t O_EW2H = O_EW1L + N_E1 * 2;
  constexpr size_t O_EW2L = O_EW2H + N_E2 * 2;
  constexpr size_t O_CBH  = O_EW2L + N_E2 * 2;
  constexpr size_t O_CBL  = O_CBH + N_CB * 2;
  constexpr size_t O_DW0  = O_CBL + N_CB * 2;
  constexpr size_t O_DW1  = O_DW0 + N_D0 * 2;
  constexpr size_t O_DW2  = O_DW1 + N_D1 * 2;
  constexpr size_t O_XH   = O_DW2 + N_D2 * 2;
  constexpr size_t O_XL   = O_XH + N_X * 2;
  constexpr size_t O_H0H  = O_XL + N_X * 2;
  constexpr size_t O_H0L  = O_H0H + N_H0 * 2;
  constexpr size_t O_H1H  = O_H0L + N_H0 * 2;
  constexpr size_t O_H1L  = O_H1H + N_H1 * 2;
  constexpr size_t O_H2H  = O_H1L + N_H1 * 2;
  constexpr size_t O_H2L  = O_H2H + N_H2 * 2;
  constexpr size_t O_FLH  = O_H2L + N_H2 * 2;
  constexpr size_t O_FLL  = O_FLH + N_FL * 2;
  constexpr size_t O_G    = O_XH;
  constexpr size_t O_INDS = O_XL;
  constexpr size_t O_CBN  = O_XL + (1ull << 17);
  constexpr size_t O_PART = O_XL + (1ull << 18);
  constexpr size_t O_Z0   = O_XL + (1ull << 20);
  constexpr size_t O_ZH1  = O_Z0 + N_H2 * 2;
  constexpr size_t O_ZH2  = O_ZH1 + N_Z1 * 2;

  char* ws = (char*)d_ws;
  f16*   XH = (f16*)(ws + O_XH);   f16* XL = (f16*)(ws + O_XL);
  f16* EW0H = (f16*)(ws + O_EW0H); f16* EW0L = (f16*)(ws + O_EW0L);
  f16* EW1H = (f16*)(ws + O_EW1H); f16* EW1L = (f16*)(ws + O_EW1L);
  f16* EW2H = (f16*)(ws + O_EW2H); f16* EW2L = (f16*)(ws + O_EW2L);
  f16*  CBH = (f16*)(ws + O_CBH);  f16* CBL = (f16*)(ws + O_CBL);
  f16*  DW0 = (f16*)(ws + O_DW0);  f16* DW1 = (f16*)(ws + O_DW1);  f16* DW2 = (f16*)(ws + O_DW2);
  f16*  H0H = (f16*)(ws + O_H0H);  f16* H0L = (f16*)(ws + O_H0L);
  f16*  H1H = (f16*)(ws + O_H1H);  f16* H1L = (f16*)(ws + O_H1L);
  f16*  H2H = (f16*)(ws + O_H2H);  f16* H2L = (f16*)(ws + O_H2L);
  f16*  FLH = (f16*)(ws + O_FLH);  f16* FLL = (f16*)(ws + O_FLL);
  float*  G = (float*)(ws + O_G);
  int* INDS = (int*)(ws + O_INDS);
  float* CBN = (float*)(ws + O_CBN);
  float* PART = (float*)(ws + O_PART);
  f16*   Z0 = (f16*)(ws + O_Z0);
  f16*  ZH1 = (f16*)(ws + O_ZH1);
  f16*  ZH2 = (f16*)(ws + O_ZH2);
  // K-split partial slabs: dec2's output region of d_out (16.78M floats),
  // rewritten by dec2 at the end — free scratch until then.
  float* PSL = out;

  // ---- 1. input conversions (fused: 2 launches) ----
  vq_prep<<<16450, 256, 0, stream>>>(x, XH, XL, out + 16777216, cb, CBH, CBL, CBN);
  vq_tsplit_all<<<21504, 256, 0, stream>>>(ew0, EW0H, EW0L, ew1, EW1H, EW1L,
                                           ew2, EW2H, EW2L, dw0, DW0, dw1, DW1, dw2, DW2);

  // ---- 2. encoder ----
  // enc0: reuse-split 256x256 5-phase, K-split x2 (NTloc=64) -> 256 blocks
  vq_gemmS<<<dim3(128, 2), 512, 0, stream>>>(
      XH, XL, EW0H, EW0L, PSL, 4096, 2048, 4096, 64);
  vq_ksum<2><<<(int)(N_H0 / 4 / 256), 256, 0, stream>>>(
      PSL, eb0, H0H, H0L, (int)N_H0, 2048, 1.0f / (SX * SW), SA);
  // enc1: reuse-split 256x256 5-phase, K-split x4 (NTloc=16) -> 256 blocks
  vq_gemmS<<<dim3(64, 4), 512, 0, stream>>>(
      H0H, H0L, EW1H, EW1L, PSL, 4096, 1024, 2048, 16);
  vq_ksum<4><<<(int)(N_H1 / 4 / 256), 256, 0, stream>>>(
      PSL, eb1, H1H, H1L, (int)N_H1, 1024, 1.0f / (SA * SW), SA);
  // enc2: 128^2 2-phase
  vq_gemm<1, 1><<<(4096 / BM) * (512 / BN), 256, 0, stream>>>(
      H1H, H1L, EW2H, EW2L, eb2, H2H, H2L, 4096, 512, 1024, 1.0f / (SA * SW), SA);

  // ---- 3. VQ ----
  vq_tpose<<<BATCH * 64, 256, 0, stream>>>(H2H, H2L, FLH, FLL);
  vq_gemm<1, 0><<<(16384 / BM) * (512 / BN), 256, 0, stream>>>(
      FLH, FLL, CBH, CBL, nullptr, G, nullptr, 16384, 512, 128, 1.0f / (SA * SCB), 0.f);
  vq_argmin<<<16384, 64, 0, stream>>>(G, CBN, INDS);
  vq_gather_loss<<<8448, 256, 0, stream>>>(cb, INDS, Z0, FLH, FLL, PART);
  vq_loss_final<<<1, 256, 0, stream>>>(PART, out + 33554432);

  // ---- 4. decoder ----
  vq_gemm<0, 2><<<(4096 / BM) * (1024 / BN), 256, 0, stream>>>(
      Z0, nullptr, DW0, nullptr, db0, ZH1, nullptr, 4096, 1024, 512, 1.0f / (SQ * SW), SQ);
  // dec1: 256x128 merged 2-phase, grid 256, NTloc = 1024/64 = 16
  vq_gemm8<0, 2, 4, 2, 4><<<dim3(256, 1), 512, 0, stream>>>(
      ZH1, nullptr, DW1, nullptr, db1, ZH2, nullptr, 4096, 2048, 1024, 16, 1.0f / (SQ * SW), SQ);
  // dec2: 256x256 8-phase, grid 256, NTloc = 2048/64 = 32 (writes out0 last)
  vq_gemm8<0, 3, 2, 4, 8><<<dim3(256, 1), 512, 0, stream>>>(
      ZH2, nullptr, DW2, nullptr, db2, out, nullptr, 4096, 4096, 2048, 32, 1.0f / (SQ * SW), 0.f);

  (void)in_sizes; (void)n_in; (void)out_size; (void)ws_size;
}

// Round 12
// 506.891 us; speedup vs baseline: 1.0142x; 1.0142x over previous
//
#include <hip/hip_runtime.h>

// ============================================================================
// VQ-VAE forward on MI355X (gfx950)
// Numerics: encoder + VQ-distance as split-f16 3-pass GEMMs
//           (Ah*Bh + Ah*Bl + Al*Bh, ~2^-22 rel err) so the codebook argmin
//           matches the fp64/np reference; decoder plain f16; fp32 accum.
// enc0/enc1: vq_gemmS — 256x256, BK=32, 4-panel double-buffer, operand reuse,
//   TIGHT 5-phase schedule (r9-verified: 170us, MfmaUtil 56.3%, 1212 TF),
//   counted vmcnt(8), K-split slabs + vq_ksum epilogue.
//   [r10 3-phase 52.8%, r7 loose 47%, r4 deep-prefetch 40% -> 5-phase optimal]
// dist GEMM: argmin fused into epilogue (bit-identical first-min semantics),
//   G matrix (64MB traffic) eliminated; vq_argmin4 reduces 4 candidates/row.
// dec1: 256x128 merged 2-phase; dec2: 256x256 8-phase (both verified).
// Fused small kernels: vq_prep, vq_tsplit_all, vq_gather_loss (r9-verified).
// ============================================================================

typedef _Float16 f16;
typedef _Float16 f16x8 __attribute__((ext_vector_type(8)));
typedef _Float16 f16x4 __attribute__((ext_vector_type(4)));
typedef float    f32x4 __attribute__((ext_vector_type(4)));

// ---- async global->LDS (width 16) ------------------------------------------
typedef const unsigned int __attribute__((address_space(1)))* gp1_t;
typedef unsigned int __attribute__((address_space(3)))*       lp3_t;

__device__ __forceinline__ void gl_lds16(const void* g, void* l) {
  __builtin_amdgcn_global_load_lds((gp1_t)g, (lp3_t)l, 16, 0, 0);
}

// ---- problem constants -----------------------------------------------------
#define BATCH 32
#define CDIM  128
#define WDIM  4096
#define LDIM  512
#define KCB   512
#define DCB   128

// scales (powers of two, exact)
#define SX    128.0f
#define SW    256.0f
#define SA    256.0f
#define SCB   4096.0f
#define SQ    4096.0f

#define G8_BAR() do { asm volatile("" ::: "memory"); \
  __builtin_amdgcn_s_barrier(); asm volatile("" ::: "memory"); } while (0)
#define G8_LGKM0() do { asm volatile("s_waitcnt lgkmcnt(0)" ::: "memory"); \
  __builtin_amdgcn_sched_barrier(0); } while (0)
#define G8_PRIO1() __builtin_amdgcn_s_setprio(1)
#define G8_PRIO0() __builtin_amdgcn_s_setprio(0)

// ============================================================================
// vq_gemmS: split GEMM with operand reuse.  C = Ah*Bh^T + Ah*Bl^T + Al*Bh^T
// 256x256 tile, 8 waves (2x4), wave tile 128x64, BK=32.
// Per buffer (64KB): [Ah 16K][Al 16K][Bh 16K][Bl 16K]; 2 buffers = 128KB.
// Swizzle (64B rows): 16B chunk c stored at c ^ ((row>>1)&3); read applies
// same XOR -> 64-lane ds_read_b128 covers all 8 slots/128B window (2/bank).
// Per kk-tile: 5 phases {16,16,16,16,32} MFMA; stages BH@P1 BL@P2 AH@P3 AL@P4
// (each >=1 barrier after that panel's last read); gate vmcnt(8).
// Writes raw f32 partial to slab blockIdx.y of Co (K-split; vq_ksum reduces).
// ============================================================================

#define GS_STAGE(src, row0, kk, off) \
  _Pragma("unroll") \
  for (int j_ = 0; j_ < 2; ++j_) { \
    const int p_ = j_ * 8192 + tid * 16; \
    const int r_ = p_ >> 6; \
    const int c_ = (p_ >> 4) & 3; \
    gl_lds16((src) + (size_t)((row0) + r_) * K + (kk) + ((c_ ^ ((r_ >> 1) & 3)) << 3), \
             smem + (off) + p_); \
  }

#define GS_ST(tt, pb, SRC, row0, poff) do { \
  const int tc_ = (tt) < NTloc ? (tt) : NTloc - 1; \
  const int kk_ = (t0 + tc_) << 5; \
  GS_STAGE(SRC, row0, kk_, (pb) * 65536 + (poff)) } while (0)

#define GS_READ_A(pb, HL, half, dst) \
  _Pragma("unroll") \
  for (int m_ = 0; m_ < 4; ++m_) { \
    const int r_ = wr * 128 + ((half) * 4 + m_) * 16 + fr; \
    dst[m_] = *(const f16x8*)(smem + (pb) * 65536 + (HL) * 16384 + r_ * 64 + swz16); \
  }

#define GS_READ_B(pb, HL, brr) \
  _Pragma("unroll") \
  for (int n_ = 0; n_ < 4; ++n_) { \
    const int r_ = wc * 64 + n_ * 16 + fr; \
    brr[n_] = *(const f16x8*)(smem + (pb) * 65536 + 32768 + (HL) * 16384 + r_ * 64 + swz16); \
  }

#define GS_MFMA(aarr, half, brr) \
  _Pragma("unroll") \
  for (int m_ = 0; m_ < 4; ++m_) \
  _Pragma("unroll") \
  for (int n_ = 0; n_ < 4; ++n_) \
    acc[(half) * 4 + m_][n_] = __builtin_amdgcn_mfma_f32_16x16x32_f16( \
        aarr[m_], brr[n_], acc[(half) * 4 + m_][n_], 0, 0, 0);

__global__ __launch_bounds__(512, 2)
void vq_gemmS(const f16* __restrict__ Ah, const f16* __restrict__ Al,
              const f16* __restrict__ Bh, const f16* __restrict__ Bl,
              float* __restrict__ Co, int M, int N, int K, int NTloc)
{
  __shared__ __align__(16) char smem[131072];

  const int tid = threadIdx.x;
  const int lane = tid & 63;
  const int w = tid >> 6;
  const int wr = w >> 2, wc = w & 3;       // 2x4 wave grid, 128x64 per wave
  const int fr = lane & 15, hq = lane >> 4;
  const int swz16 = (hq ^ ((fr >> 1) & 3)) << 4;

  const int nbx = N / 256;
  const int cpx = (int)gridDim.x >> 3;     // gridDim.x % 8 == 0
  const int swzb = ((int)blockIdx.x & 7) * cpx + ((int)blockIdx.x >> 3);
  const int bx = swzb % nbx, by = swzb / nbx;
  const int m0 = by * 256, n0 = bx * 256;
  const int t0 = (int)blockIdx.y * NTloc;  // kk-tile (32-wide) offset

  f32x4 acc[8][4] = {};
  f16x8 ah0[4], ah1[4], al0[4], al1[4], bh[4], bl[4];

  // ---- prologue: tiles 0 and 1 (8 loads each, FIFO per tile) ----
  GS_ST(0, 0, Bh, n0, 32768); GS_ST(0, 0, Bl, n0, 49152);
  GS_ST(0, 0, Ah, m0, 0);     GS_ST(0, 0, Al, m0, 16384);
  GS_ST(1, 1, Bh, n0, 32768); GS_ST(1, 1, Bl, n0, 49152);
  GS_ST(1, 1, Ah, m0, 0);     GS_ST(1, 1, Al, m0, 16384);

  int pb = 0;
  for (int t = 0; t < NTloc; ++t) {
    asm volatile("s_waitcnt vmcnt(8)" ::: "memory");   // tile t landed; t+1 in flight
    G8_BAR();
    // P0: reads ah[0..3], bh
    GS_READ_A(pb, 0, 0, ah0) GS_READ_B(pb, 0, bh)
    G8_BAR(); G8_LGKM0();
    G8_PRIO1(); GS_MFMA(ah0, 0, bh) G8_PRIO0();
    G8_BAR();
    // P1: reads al[0..3], bl; stage BH(t+2) [Bh reads done P0]
    GS_READ_A(pb, 1, 0, al0) GS_READ_B(pb, 1, bl)
    GS_ST(t + 2, pb, Bh, n0, 32768);
    G8_BAR(); G8_LGKM0();
    G8_PRIO1(); GS_MFMA(ah0, 0, bl) G8_PRIO0();
    G8_BAR();
    // P2: reads ah[4..7]; stage BL(t+2) [Bl reads done P1]
    GS_READ_A(pb, 0, 1, ah1)
    GS_ST(t + 2, pb, Bl, n0, 49152);
    G8_BAR(); G8_LGKM0();
    G8_PRIO1(); GS_MFMA(al0, 0, bh) G8_PRIO0();
    G8_BAR();
    // P3: reads al[4..7]; stage AH(t+2) [Ah reads done P2]
    GS_READ_A(pb, 1, 1, al1)
    GS_ST(t + 2, pb, Ah, m0, 0);
    G8_BAR(); G8_LGKM0();
    G8_PRIO1(); GS_MFMA(ah1, 1, bh) G8_PRIO0();
    G8_BAR();
    // P4: stage AL(t+2) [Al reads done P3]; 32 MFMA (all regs complete)
    GS_ST(t + 2, pb, Al, m0, 16384);
    G8_PRIO1(); GS_MFMA(ah1, 1, bl) GS_MFMA(al1, 1, bh) G8_PRIO0();
    pb ^= 1;
    // closing gate is next iteration's head
  }

  // ---- epilogue: raw f32 partials to slab blockIdx.y ----
  float* Pslab = Co + (size_t)blockIdx.y * M * N;
  const int r4 = hq * 4;
#pragma unroll
  for (int mi = 0; mi < 8; ++mi) {
#pragma unroll
    for (int ni = 0; ni < 4; ++ni) {
      const int col = n0 + wc * 64 + ni * 16 + fr;
#pragma unroll
      for (int j = 0; j < 4; ++j) {
        const int row = m0 + wr * 128 + mi * 16 + r4 + j;
        Pslab[(size_t)row * N + col] = acc[mi][ni][j];
      }
    }
  }
}

// ============================================================================
// 8-wave GEMM (decoder): C[M,N] = A[M,K] @ B^T[N,K]  (non-split paths)
// ============================================================================

#define G8_SRC(t, As, Bs, kk) \
  const f16 *As, *Bs; int kk; \
  { int ts_ = (t) < NTloc ? (t) : NTloc - 1; int kg_ = (t0 + ts_) << 6; \
    if (SPLIT) { int sg_ = (kg_ >= 2 * K) ? 2 : ((kg_ >= K) ? 1 : 0); \
      kk = kg_ - sg_ * K; As = (sg_ == 2) ? Al : Ah; Bs = (sg_ == 1) ? Bl : Bh; } \
    else { As = Ah; Bs = Bh; kk = kg_; } }

#define G8_STAGE(src, row0, kk, off) \
  _Pragma("unroll") \
  for (int j_ = 0; j_ < 2; ++j_) { \
    const int p_ = j_ * 8192 + tid * 16; \
    const int r_ = p_ >> 7; \
    const int c_ = (p_ >> 4) & 7; \
    gl_lds16((src) + (size_t)((row0) + r_) * K + (kk) + ((c_ ^ (r_ & 7)) << 3), \
             smem + (off) + p_); \
  }

#define G8_STAGE_A(t, u) do { G8_SRC(t, As_, Bs_, kk_) \
  G8_STAGE(As_, m0 + (u) * 128, kk_, ((t) & 1) * ASZ + (u) * 16384) } while (0)
#define G8_STAGE_B(t, u) do { G8_SRC(t, As_, Bs_, kk_) \
  G8_STAGE(Bs_, n0 + (u) * 128, kk_, BBASE + ((t) & 1) * BSZ + (u) * 16384) } while (0)

#define G8_READ_A(buf, mh) \
  _Pragma("unroll") \
  for (int m_ = 0; m_ < MR2; ++m_) { \
    const int r_ = wr * (MR * 16) + ((mh) * MR2 + m_) * 16 + fr; \
    _Pragma("unroll") \
    for (int ks_ = 0; ks_ < 2; ++ks_) \
      ar[m_][ks_] = *(const f16x8*)(smem + (buf) * ASZ + r_ * 128 + \
                                    ((((ks_ << 2) + hq) ^ (r_ & 7)) << 4)); \
  }

#define G8_READ_B(buf, nh, br) \
  _Pragma("unroll") \
  for (int n_ = 0; n_ < 2; ++n_) { \
    const int r_ = wc * 64 + ((nh) * 2 + n_) * 16 + fr; \
    _Pragma("unroll") \
    for (int ks_ = 0; ks_ < 2; ++ks_) \
      br[n_][ks_] = *(const f16x8*)(smem + BBASE + (buf) * BSZ + r_ * 128 + \
                                    ((((ks_ << 2) + hq) ^ (r_ & 7)) << 4)); \
  }

#define G8_MFMA(mh, nh, br) \
  _Pragma("unroll") \
  for (int m_ = 0; m_ < MR2; ++m_) \
  _Pragma("unroll") \
  for (int n_ = 0; n_ < 2; ++n_) \
  _Pragma("unroll") \
  for (int ks_ = 0; ks_ < 2; ++ks_) \
    acc[(mh) * MR2 + m_][(nh) * 2 + n_] = __builtin_amdgcn_mfma_f32_16x16x32_f16( \
        ar[m_][ks_], br[n_][ks_], acc[(mh) * MR2 + m_][(nh) * 2 + n_], 0, 0, 0);

#define G8_VMGATE() do { \
  if constexpr (BUNITS == 2) asm volatile("s_waitcnt vmcnt(4)" ::: "memory"); \
  else                       asm volatile("s_waitcnt vmcnt(2)" ::: "memory"); } while (0)

template<int SPLIT, int EPI, int WM, int WN, int MR>
__global__ __launch_bounds__(512, 2)
void vq_gemm8(const f16* __restrict__ Ah, const f16* __restrict__ Al,
              const f16* __restrict__ Bh, const f16* __restrict__ Bl,
              const float* __restrict__ bias,
              void* __restrict__ Co, void* __restrict__ Co2,
              int M, int N, int K, int NTloc, float unscale, float outscale)
{
  constexpr int MR2 = MR / 2;
  constexpr int GBM = WM * MR * 16;      // 256
  constexpr int GBN = WN * 64;           // 128 or 256
  constexpr int BUNITS = GBN / 128;      // 1 or 2
  constexpr int ASZ = GBM * 128;         // bytes per A buffer (32KB)
  constexpr int BSZ = GBN * 128;         // bytes per B buffer
  constexpr int BBASE = 2 * ASZ;
  constexpr int LDSZ = 2 * ASZ + 2 * BSZ;  // 96KB / 128KB

  __shared__ __align__(16) char smem[LDSZ];

  const int tid = threadIdx.x;
  const int lane = tid & 63;
  const int w = tid >> 6;
  const int wr = w / WN, wc = w % WN;
  const int fr = lane & 15, hq = lane >> 4;

  const int nbx = N / GBN;
  const int cpx = (int)gridDim.x >> 3;   // gridDim.x % 8 == 0 at all call sites
  const int swz = ((int)blockIdx.x & 7) * cpx + ((int)blockIdx.x >> 3);
  const int bx = swz % nbx, by = swz / nbx;
  const int m0 = by * GBM, n0 = bx * GBN;
  const int t0 = (int)blockIdx.y * NTloc;

  const int NI = NTloc >> 1;

  f32x4 acc[MR][4] = {};
  f16x8 ar[MR2][2], br0[2][2], br1[2][2];

  // ---- prologue: tile0 complete + tile1 B unit(s) (order drives vmcnt) ----
  G8_STAGE_B(0, 0); if constexpr (BUNITS == 2) G8_STAGE_B(0, 1);
  G8_STAGE_A(0, 0); G8_STAGE_A(0, 1);
  G8_STAGE_B(1, 0); if constexpr (BUNITS == 2) G8_STAGE_B(1, 1);

  for (int i = 0; i < NI; ++i) {
    const int to = 2 * i + 1, te = 2 * i + 2, to2 = 2 * i + 3;
    if constexpr (BUNITS == 1) {
      // ---- merged: 2 phases per K-tile, 16 MFMA per phase (round-3) ----
      G8_VMGATE(); G8_BAR();
      G8_READ_A(0, 0) G8_READ_B(0, 0, br0) G8_READ_B(0, 1, br1)
      G8_STAGE_A(to, 0); G8_STAGE_A(to, 1);
      G8_BAR(); G8_LGKM0();
      G8_PRIO1(); G8_MFMA(0, 0, br0) G8_MFMA(0, 1, br1) G8_PRIO0();
      G8_BAR();
      G8_READ_A(0, 1)
      G8_STAGE_B(te, 0);
      G8_BAR(); G8_LGKM0();
      G8_PRIO1(); G8_MFMA(1, 0, br0) G8_MFMA(1, 1, br1) G8_PRIO0();
      G8_VMGATE(); G8_BAR();
      G8_READ_A(1, 0) G8_READ_B(1, 0, br0) G8_READ_B(1, 1, br1)
      G8_STAGE_A(te, 0); G8_STAGE_A(te, 1);
      G8_BAR(); G8_LGKM0();
      G8_PRIO1(); G8_MFMA(0, 0, br0) G8_MFMA(0, 1, br1) G8_PRIO0();
      G8_BAR();
      G8_READ_A(1, 1)
      G8_STAGE_B(to2, 0);
      G8_BAR(); G8_LGKM0();
      G8_PRIO1(); G8_MFMA(1, 0, br0) G8_MFMA(1, 1, br1) G8_PRIO0();
    } else {
      // ---- 256x256: 8-phase m201 shape, 16 MFMA per phase ----
      G8_VMGATE(); G8_BAR();
      G8_READ_A(0, 0) G8_READ_B(0, 0, br0)
      G8_STAGE_A(to, 0);
      G8_BAR(); G8_LGKM0(); G8_PRIO1(); G8_MFMA(0, 0, br0) G8_PRIO0();
      G8_BAR();
      G8_READ_B(0, 1, br1)
      G8_STAGE_A(to, 1);
      G8_BAR(); G8_LGKM0(); G8_PRIO1(); G8_MFMA(0, 1, br1) G8_PRIO0();
      G8_BAR();
      G8_READ_A(0, 1)
      G8_STAGE_B(te, 0);
      G8_BAR(); G8_LGKM0(); G8_PRIO1(); G8_MFMA(1, 0, br0) G8_PRIO0();
      G8_BAR();
      G8_STAGE_B(te, 1);
      G8_BAR(); G8_PRIO1(); G8_MFMA(1, 1, br1) G8_PRIO0();
      G8_VMGATE(); G8_BAR();
      G8_READ_A(1, 0) G8_READ_B(1, 0, br0)
      G8_STAGE_A(te, 0);
      G8_BAR(); G8_LGKM0(); G8_PRIO1(); G8_MFMA(0, 0, br0) G8_PRIO0();
      G8_BAR();
      G8_READ_B(1, 1, br1)
      G8_STAGE_A(te, 1);
      G8_BAR(); G8_LGKM0(); G8_PRIO1(); G8_MFMA(0, 1, br1) G8_PRIO0();
      G8_BAR();
      G8_READ_A(1, 1)
      G8_STAGE_B(to2, 0);
      G8_BAR(); G8_LGKM0(); G8_PRIO1(); G8_MFMA(1, 0, br0) G8_PRIO0();
      G8_BAR();
      G8_STAGE_B(to2, 1);
      G8_BAR(); G8_PRIO1(); G8_MFMA(1, 1, br1) G8_PRIO0();
    }
  }

  // ---- epilogue ----
  const int r4 = hq * 4;
#pragma unroll
  for (int mi = 0; mi < MR; ++mi) {
#pragma unroll
    for (int ni = 0; ni < 4; ++ni) {
      const int col = n0 + wc * 64 + ni * 16 + fr;
      const float bv = (EPI == 0) ? 0.f : bias[col];
#pragma unroll
      for (int j = 0; j < 4; ++j) {
        const int row = m0 + wr * (MR * 16) + mi * 16 + r4 + j;
        const size_t idx = (size_t)row * N + col;
        float y = acc[mi][ni][j] * unscale;
        if (EPI != 0) y += bv;
        if (EPI == 1 || EPI == 2) y = fmaxf(y, 0.f);
        if (EPI == 0 || EPI == 3) ((float*)Co)[idx] = y;
        else {
          const float ys = y * outscale;
          const f16 hv = (f16)ys;
          ((f16*)Co)[idx] = hv;
          if (EPI == 1) ((f16*)Co2)[idx] = (f16)(ys - (float)hv);
        }
      }
    }
  }
}

// ---- K-split reduction epilogue: sum NS slabs + bias + relu + hi/lo split --
template<int NS>
__global__ void vq_ksum(const float* __restrict__ P, const float* __restrict__ bias,
                        f16* __restrict__ Oh, f16* __restrict__ Ol,
                        int MN, int N, float unscale, float outscale)
{
  const int i4 = (blockIdx.x * 256 + threadIdx.x) * 4;
  if (i4 >= MN) return;
  float4 s = ((const float4*)P)[i4 >> 2];
#pragma unroll
  for (int sl = 1; sl < NS; ++sl) {
    const float4 v = ((const float4*)(P + (size_t)sl * MN))[i4 >> 2];
    s.x += v.x; s.y += v.y; s.z += v.z; s.w += v.w;
  }
  const int col = i4 % N;   // N % 4 == 0, i4..i4+3 share the row
  f16x4 h, l;
#pragma unroll
  for (int j = 0; j < 4; ++j) {
    float y = (&s.x)[j] * unscale + bias[col + j];
    y = fmaxf(y, 0.f) * outscale;
    const f16 hv = (f16)y;
    h[j] = hv;
    l[j] = (f16)(y - (float)hv);
  }
  *(f16x4*)&Oh[i4] = h;
  *(f16x4*)&Ol[i4] = l;
}

// ============================================================================
// 2-phase 128^2 GEMM (verified round-1) for the small/odd-shaped GEMMs
// EPI 5: dist GEMM + fused per-tile argmin. bias = codebook row norms cbn;
//   Co = CANDV [M][4] f32, Co2 = CANDI [M][4] int (per column-tile candidate).
//   First-min semantics preserved exactly: (d, idx) lexicographic compare at
//   every stage, reduction orders = increasing column index.
// ============================================================================
#define BM 128
#define BN 128
#define BK 32

template<int SPLIT, int EPI>
__global__ __launch_bounds__(256, 2)
void vq_gemm(const f16* __restrict__ Ah, const f16* __restrict__ Al,
             const f16* __restrict__ Bh, const f16* __restrict__ Bl,
             const float* __restrict__ bias,
             void* __restrict__ Co, void* __restrict__ Co2,
             int M, int N, int K, float unscale, float outscale)
{
  __shared__ __align__(16) f16 sAh[BM * BK];
  __shared__ __align__(16) f16 sBh[BN * BK];
  __shared__ __align__(16) f16 sAl[SPLIT ? BM * BK : 8];
  __shared__ __align__(16) f16 sBl[SPLIT ? BN * BK : 8];

  const int tid  = threadIdx.x;
  const int lane = tid & 63;
  const int w    = tid >> 6;
  const int nb   = N / BN;
  const int bx   = blockIdx.x % nb;
  const int by   = blockIdx.x / nb;
  const int m0   = by * BM, n0 = bx * BN;
  const int wr   = w >> 1, wc = w & 1;
  const int fr   = lane & 15;
  const int ko   = (lane >> 4) * 8;

  f32x4 acc[4][4] = {};

  const int srow = lane >> 2;
  const int skb  = (lane & 3) * 8;

  for (int k0 = 0; k0 < K; k0 += BK) {
#pragma unroll
    for (int i = 0; i < 2; ++i) {
      const int c  = w * 2 + i;
      const size_t ga = (size_t)(m0 + c * 16 + srow) * K + k0 + skb;
      const size_t gb = (size_t)(n0 + c * 16 + srow) * K + k0 + skb;
      gl_lds16(Ah + ga, &sAh[c * 512]);
      gl_lds16(Bh + gb, &sBh[c * 512]);
      if (SPLIT) {
        gl_lds16(Al + ga, &sAl[c * 512]);
        gl_lds16(Bl + gb, &sBl[c * 512]);
      }
    }
    __syncthreads();

    f16x8 ah[4], bh[4], al[4], bl[4];
#pragma unroll
    for (int mi = 0; mi < 4; ++mi) {
      const int r = (wr * 64 + mi * 16 + fr) * BK + ko;
      ah[mi] = *(const f16x8*)&sAh[r];
      if (SPLIT) al[mi] = *(const f16x8*)&sAl[r];
    }
#pragma unroll
    for (int ni = 0; ni < 4; ++ni) {
      const int r = (wc * 64 + ni * 16 + fr) * BK + ko;
      bh[ni] = *(const f16x8*)&sBh[r];
      if (SPLIT) bl[ni] = *(const f16x8*)&sBl[r];
    }
#pragma unroll
    for (int mi = 0; mi < 4; ++mi)
#pragma unroll
      for (int ni = 0; ni < 4; ++ni) {
        acc[mi][ni] = __builtin_amdgcn_mfma_f32_16x16x32_f16(ah[mi], bh[ni], acc[mi][ni], 0, 0, 0);
        if (SPLIT) {
          acc[mi][ni] = __builtin_amdgcn_mfma_f32_16x16x32_f16(ah[mi], bl[ni], acc[mi][ni], 0, 0, 0);
          acc[mi][ni] = __builtin_amdgcn_mfma_f32_16x16x32_f16(al[mi], bh[ni], acc[mi][ni], 0, 0, 0);
        }
      }
    __syncthreads();
  }

  const int r4 = (lane >> 4) * 4;

  if constexpr (EPI == 5) {
    // ---- fused argmin: d = cbn[col] - 2*y, first-min over this 128-col tile
    __shared__ float cv[2][128];
    __shared__ int   ci[2][128];
#pragma unroll
    for (int mi = 0; mi < 4; ++mi) {
#pragma unroll
      for (int j = 0; j < 4; ++j) {
        float best = 1e30f; int bi = 0;
#pragma unroll
        for (int ni = 0; ni < 4; ++ni) {      // increasing local column order
          const int colL = wc * 64 + ni * 16 + fr;
          const float d = bias[n0 + colL] - 2.0f * (acc[mi][ni][j] * unscale);
          if (d < best || (d == best && colL < bi)) { best = d; bi = colL; }
        }
#pragma unroll
        for (int off = 8; off; off >>= 1) {   // reduce across the 16 fr lanes
          const float ov = __shfl_xor(best, off);
          const int oi = __shfl_xor(bi, off);
          if (ov < best || (ov == best && oi < bi)) { best = ov; bi = oi; }
        }
        if (fr == 0) {
          const int lr = wr * 64 + mi * 16 + r4 + j;   // 0..127
          cv[wc][lr] = best; ci[wc][lr] = bi;
        }
      }
    }
    __syncthreads();
    if (tid < 128) {                          // combine the two column-waves
      const float v0 = cv[0][tid], v1 = cv[1][tid];
      const int i0 = ci[0][tid], i1 = ci[1][tid];
      float v; int ii;
      if (v1 < v0 || (v1 == v0 && i1 < i0)) { v = v1; ii = i1; }
      else                                  { v = v0; ii = i0; }
      ((float*)Co)[(size_t)(m0 + tid) * 4 + bx] = v;
      ((int*)Co2)[(size_t)(m0 + tid) * 4 + bx] = ii + n0;
    }
    return;
  }

#pragma unroll
  for (int mi = 0; mi < 4; ++mi) {
#pragma unroll
    for (int ni = 0; ni < 4; ++ni) {
      const int col = n0 + wc * 64 + ni * 16 + fr;
      const float bv = (EPI == 0) ? 0.0f : bias[col];
#pragma unroll
      for (int j = 0; j < 4; ++j) {
        const int row = m0 + wr * 64 + mi * 16 + r4 + j;
        float y = acc[mi][ni][j] * unscale;
        if (EPI != 0) y += bv;
        if (EPI == 1 || EPI == 2) y = fmaxf(y, 0.0f);
        const size_t idx = (size_t)row * N + col;
        if (EPI == 0 || EPI == 3) {
          ((float*)Co)[idx] = y;
        } else {
          const float ys = y * outscale;
          const f16 hv = (f16)ys;
          ((f16*)Co)[idx] = hv;
          if (EPI == 1) ((f16*)Co2)[idx] = (f16)(ys - (float)hv);
        }
      }
    }
  }
}

// ---- final argmin over the 4 per-tile candidates (ordered by column tile) --
__global__ void vq_argmin4(const float* __restrict__ CV, const int* __restrict__ CI,
                           int* __restrict__ inds)
{
  const int r = blockIdx.x * 256 + threadIdx.x;
  if (r >= BATCH * LDIM) return;
  float best = CV[(size_t)r * 4]; int bi = CI[(size_t)r * 4];
#pragma unroll
  for (int b = 1; b < 4; ++b) {
    const float v = CV[(size_t)r * 4 + b];
    const int i = CI[(size_t)r * 4 + b];
    if (v < best || (v == best && i < bi)) { best = v; bi = i; }
  }
  inds[r] = bi;
}

// ---- fused prep: x-split (+exact out1 copy) | cb-split | cbnorm ------------
__global__ void vq_prep(const float* __restrict__ x, f16* __restrict__ XH,
                        f16* __restrict__ XL, float* __restrict__ raw,
                        const float* __restrict__ cb, f16* __restrict__ CBH,
                        f16* __restrict__ CBL, float* __restrict__ cbn)
{
  const int b = blockIdx.x;
  if (b < 16384) {                     // x: 16384 blocks x 256 thr x 4 elems
    const int i = b * 256 + threadIdx.x;
    const float4 v = ((const float4*)x)[i];
    ((float4*)raw)[i] = v;             // output 1: exact copy
    f16x4 h, l;
#pragma unroll
    for (int j = 0; j < 4; ++j) {
      const float s = (&v.x)[j] * SX;
      const f16 hh = (f16)s;
      h[j] = hh;
      l[j] = (f16)(s - (float)hh);
    }
    *(f16x4*)&XH[i * 4] = h;
    *(f16x4*)&XL[i * 4] = l;
  } else if (b < 16448) {              // cb split: 64 blocks (512*128/4/256)
    const int i = (b - 16384) * 256 + threadIdx.x;
    const float4 v = ((const float4*)cb)[i];
    f16x4 h, l;
#pragma unroll
    for (int j = 0; j < 4; ++j) {
      const float s = (&v.x)[j] * SCB;
      const f16 hh = (f16)s;
      h[j] = hh;
      l[j] = (f16)(s - (float)hh);
    }
    *(f16x4*)&CBH[i * 4] = h;
    *(f16x4*)&CBL[i * 4] = l;
  } else {                             // cbnorm: 2 blocks
    const int k = (b - 16448) * 256 + threadIdx.x;
    if (k < KCB) {
      float s = 0.f;
      for (int c = 0; c < DCB; ++c) { const float v = cb[k * DCB + c]; s += v * v; }
      cbn[k] = s;
    }
  }
}

// ---- fused weight transpose+split: all 6 weights in one launch -------------
__global__ void vq_tsplit_all(
    const float* __restrict__ ew0, f16* __restrict__ EW0H, f16* __restrict__ EW0L,
    const float* __restrict__ ew1, f16* __restrict__ EW1H, f16* __restrict__ EW1L,
    const float* __restrict__ ew2, f16* __restrict__ EW2H, f16* __restrict__ EW2L,
    const float* __restrict__ dw0, f16* __restrict__ DW0,
    const float* __restrict__ dw1, f16* __restrict__ DW1,
    const float* __restrict__ dw2, f16* __restrict__ DW2)
{
  __shared__ float t[32][33];
  int b = blockIdx.x;
  const float* W; f16* Th; f16* Tl; int K, N, gx, wl;
  if (b < 8192)        { W = ew0; Th = EW0H; Tl = EW0L; K = 4096; N = 2048; gx = 64;  wl = 1; }
  else if (b < 10240)  { b -= 8192;  W = ew1; Th = EW1H; Tl = EW1L; K = 2048; N = 1024; gx = 32;  wl = 1; }
  else if (b < 10752)  { b -= 10240; W = ew2; Th = EW2H; Tl = EW2L; K = 1024; N = 512;  gx = 16;  wl = 1; }
  else if (b < 11264)  { b -= 10752; W = dw0; Th = DW0;  Tl = nullptr; K = 512;  N = 1024; gx = 32;  wl = 0; }
  else if (b < 13312)  { b -= 11264; W = dw1; Th = DW1;  Tl = nullptr; K = 1024; N = 2048; gx = 64;  wl = 0; }
  else                 { b -= 13312; W = dw2; Th = DW2;  Tl = nullptr; K = 2048; N = 4096; gx = 128; wl = 0; }
  const int n0 = (b % gx) * 32, k0 = (b / gx) * 32;
  const int tx = threadIdx.x & 31, ty = threadIdx.x >> 5;
#pragma unroll
  for (int i = 0; i < 4; ++i)
    t[ty + i * 8][tx] = W[(size_t)(k0 + ty + i * 8) * N + n0 + tx];
  __syncthreads();
#pragma unroll
  for (int i = 0; i < 4; ++i) {
    const int n = n0 + ty + i * 8;
    const float v = t[tx][ty + i * 8] * SW;
    const f16 hv = (f16)v;
    Th[(size_t)n * K + k0 + tx] = hv;
    if (wl) Tl[(size_t)n * K + k0 + tx] = (f16)(v - (float)hv);
  }
}

// ---- transpose H2[(b,c),l] -> flat[(b,l),c] for hi/lo pair -----------------
__global__ void vq_tpose(const f16* __restrict__ Hh, const f16* __restrict__ Hl,
                         f16* __restrict__ Fh, f16* __restrict__ Fl)
{
  __shared__ f16 th[32][33];
  __shared__ f16 tl[32][33];
  const int bidx = blockIdx.x;
  const int b = bidx >> 6, rem = bidx & 63;
  const int l0 = (rem >> 2) * 32, c0 = (rem & 3) * 32;
  const int tx = threadIdx.x & 31, ty = threadIdx.x >> 5;
  const size_t hbase = (size_t)b * CDIM * LDIM;
#pragma unroll
  for (int i = 0; i < 4; ++i) {
    const int c = c0 + ty + i * 8;
    th[ty + i * 8][tx] = Hh[hbase + (size_t)c * LDIM + l0 + tx];
    tl[ty + i * 8][tx] = Hl[hbase + (size_t)c * LDIM + l0 + tx];
  }
  __syncthreads();
  const size_t fbase = (size_t)b * LDIM * DCB;
#pragma unroll
  for (int i = 0; i < 4; ++i) {
    const int l = l0 + ty + i * 8;
    Fh[fbase + (size_t)l * DCB + c0 + tx] = th[tx][ty + i * 8];
    Fl[fbase + (size_t)l * DCB + c0 + tx] = tl[tx][ty + i * 8];
  }
}

// ---- fused gather + loss (both depend only on inds) ------------------------
// gather: 8192 blocks (BATCH*CDIM*LDIM/256 = 2097152/256); loss: 256 blocks.
__global__ void vq_gather_loss(const float* __restrict__ cb, const int* __restrict__ inds,
                               f16* __restrict__ z0,
                               const f16* __restrict__ Fh, const f16* __restrict__ Fl,
                               float* __restrict__ partials)
{
  if (blockIdx.x < 8192) {
    // gather: z0[(b,c),l] = cb[ind[b,l]][c] * SQ
    const int t = blockIdx.x * 256 + threadIdx.x;   // t < 2097152
    const int l = t & 511, c = (t >> 9) & 127, b = t >> 16;  // b < 32
    const int ind = inds[b * LDIM + l];
    z0[t] = (f16)(cb[ind * DCB + c] * SQ);
  } else {
    // loss partials: 256 virtual blocks
    const int bid = blockIdx.x - 8192;
    const int gw = (bid * 256 + threadIdx.x) >> 6;
    const int lane = threadIdx.x & 63;
    float s = 0.f;
    for (int r = gw; r < BATCH * LDIM; r += 1024) {
      const int ind = inds[r];
      const f16* fh = Fh + (size_t)r * DCB;
      const f16* fl = Fl + (size_t)r * DCB;
      const float* q = cb + (size_t)ind * DCB;
#pragma unroll
      for (int j = 0; j < 2; ++j) {
        const int c = j * 64 + lane;
        const float lat = ((float)fh[c] + (float)fl[c]) * (1.0f / SA);
        const float d = q[c] - lat;
        s += d * d;
      }
    }
    for (int off = 32; off; off >>= 1) s += __shfl_xor(s, off);
    __shared__ float wsum[4];
    if (lane == 0) wsum[threadIdx.x >> 6] = s;
    __syncthreads();
    if (threadIdx.x == 0) partials[bid] = wsum[0] + wsum[1] + wsum[2] + wsum[3];
  }
}

__global__ void vq_loss_final(const float* __restrict__ partials, float* __restrict__ out)
{
  float s = partials[threadIdx.x];
  for (int off = 32; off; off >>= 1) s += __shfl_xor(s, off);
  __shared__ float wsum[4];
  if ((threadIdx.x & 63) == 0) wsum[threadIdx.x >> 6] = s;
  __syncthreads();
  if (threadIdx.x == 0)
    out[0] = (wsum[0] + wsum[1] + wsum[2] + wsum[3]) * (1.25f / (float)(BATCH * LDIM * DCB));
}

// ============================================================================
// launch
// ============================================================================
extern "C" void kernel_launch(void* const* d_in, const int* in_sizes, int n_in,
                              void* d_out, int out_size, void* d_ws, size_t ws_size,
                              hipStream_t stream)
{
  const float* x   = (const float*)d_in[0];
  const float* ew0 = (const float*)d_in[1];
  const float* eb0 = (const float*)d_in[2];
  const float* ew1 = (const float*)d_in[3];
  const float* eb1 = (const float*)d_in[4];
  const float* ew2 = (const float*)d_in[5];
  const float* eb2 = (const float*)d_in[6];
  const float* cb  = (const float*)d_in[7];
  const float* dw0 = (const float*)d_in[8];
  const float* db0 = (const float*)d_in[9];
  const float* dw1 = (const float*)d_in[10];
  const float* db1 = (const float*)d_in[11];
  const float* dw2 = (const float*)d_in[12];
  const float* db2 = (const float*)d_in[13];
  float* out = (float*)d_out;

  constexpr size_t N_X  = 4096ull * 4096;
  constexpr size_t N_E0 = 4096ull * 2048, N_E1 = 2048ull * 1024, N_E2 = 1024ull * 512;
  constexpr size_t N_CB = 512ull * 128;
  constexpr size_t N_D0 = 512ull * 1024, N_D1 = 1024ull * 2048, N_D2 = 2048ull * 4096;
  constexpr size_t N_H0 = 4096ull * 2048, N_H1 = 4096ull * 1024, N_H2 = 4096ull * 512;
  constexpr size_t N_FL = 16384ull * 128;
  constexpr size_t N_Z1 = 4096ull * 1024;

  constexpr size_t O_EW0H = 0;
  constexpr size_t O_EW0L = O_EW0H + N_E0 * 2;
  constexpr size_t O_EW1H = O_EW0L + N_E0 * 2;
  constexpr size_t O_EW1L = O_EW1H + N_E1 * 2;
  constexpr size_t O_EW2H = O_EW1L + N_E1 * 2;
  constexpr size_t O_EW2L = O_EW2H + N_E2 * 2;
  constexpr size_t O_CBH  = O_EW2L + N_E2 * 2;
  constexpr size_t O_CBL  = O_CBH + N_CB * 2;
  constexpr size_t O_DW0  = O_CBL + N_CB * 2;
  constexpr size_t O_DW1  = O_DW0 + N_D0 * 2;
  constexpr size_t O_DW2  = O_DW1 + N_D1 * 2;
  constexpr size_t O_XH   = O_DW2 + N_D2 * 2;
  constexpr size_t O_XL   = O_XH + N_X * 2;
  constexpr size_t O_H0H  = O_XL + N_X * 2;
  constexpr size_t O_H0L  = O_H0H + N_H0 * 2;
  constexpr size_t O_H1H  = O_H0L + N_H0 * 2;
  constexpr size_t O_H1L  = O_H1H + N_H1 * 2;
  constexpr size_t O_H2H  = O_H1L + N_H1 * 2;
  constexpr size_t O_H2L  = O_H2H + N_H2 * 2;
  constexpr size_t O_FLH  = O_H2L + N_H2 * 2;
  constexpr size_t O_FLL  = O_FLH + N_FL * 2;
  // reused regions (X dead after enc0)
  constexpr size_t O_CANDV = O_XH;                  // 16384*4*4B = 256KB
  constexpr size_t O_CANDI = O_XH + (1ull << 18);
  constexpr size_t O_INDS = O_XL;
  constexpr size_t O_CBN  = O_XL + (1ull << 17);
  constexpr size_t O_PART = O_XL + (1ull << 18);
  constexpr size_t O_Z0   = O_XL + (1ull << 20);
  constexpr size_t O_ZH1  = O_Z0 + N_H2 * 2;
  constexpr size_t O_ZH2  = O_ZH1 + N_Z1 * 2;

  char* ws = (char*)d_ws;
  f16*   XH = (f16*)(ws + O_XH);   f16* XL = (f16*)(ws + O_XL);
  f16* EW0H = (f16*)(ws + O_EW0H); f16* EW0L = (f16*)(ws + O_EW0L);
  f16* EW1H = (f16*)(ws + O_EW1H); f16* EW1L = (f16*)(ws + O_EW1L);
  f16* EW2H = (f16*)(ws + O_EW2H); f16* EW2L = (f16*)(ws + O_EW2L);
  f16*  CBH = (f16*)(ws + O_CBH);  f16* CBL = (f16*)(ws + O_CBL);
  f16*  DW0 = (f16*)(ws + O_DW0);  f16* DW1 = (f16*)(ws + O_DW1);  f16* DW2 = (f16*)(ws + O_DW2);
  f16*  H0H = (f16*)(ws + O_H0H);  f16* H0L = (f16*)(ws + O_H0L);
  f16*  H1H = (f16*)(ws + O_H1H);  f16* H1L = (f16*)(ws + O_H1L);
  f16*  H2H = (f16*)(ws + O_H2H);  f16* H2L = (f16*)(ws + O_H2L);
  f16*  FLH = (f16*)(ws + O_FLH);  f16* FLL = (f16*)(ws + O_FLL);
  float* CANDV = (float*)(ws + O_CANDV);
  int*   CANDI = (int*)(ws + O_CANDI);
  int* INDS = (int*)(ws + O_INDS);
  float* CBN = (float*)(ws + O_CBN);
  float* PART = (float*)(ws + O_PART);
  f16*   Z0 = (f16*)(ws + O_Z0);
  f16*  ZH1 = (f16*)(ws + O_ZH1);
  f16*  ZH2 = (f16*)(ws + O_ZH2);
  // K-split partial slabs: dec2's output region of d_out (16.78M floats),
  // rewritten by dec2 at the end — free scratch until then.
  float* PSL = out;

  // ---- 1. input conversions (fused: 2 launches) ----
  vq_prep<<<16450, 256, 0, stream>>>(x, XH, XL, out + 16777216, cb, CBH, CBL, CBN);
  vq_tsplit_all<<<21504, 256, 0, stream>>>(ew0, EW0H, EW0L, ew1, EW1H, EW1L,
                                           ew2, EW2H, EW2L, dw0, DW0, dw1, DW1, dw2, DW2);

  // ---- 2. encoder ----
  // enc0: reuse-split 256x256 5-phase, K-split x2 (NTloc=64) -> 256 blocks
  vq_gemmS<<<dim3(128, 2), 512, 0, stream>>>(
      XH, XL, EW0H, EW0L, PSL, 4096, 2048, 4096, 64);
  vq_ksum<2><<<(int)(N_H0 / 4 / 256), 256, 0, stream>>>(
      PSL, eb0, H0H, H0L, (int)N_H0, 2048, 1.0f / (SX * SW), SA);
  // enc1: reuse-split 256x256 5-phase, K-split x4 (NTloc=16) -> 256 blocks
  vq_gemmS<<<dim3(64, 4), 512, 0, stream>>>(
      H0H, H0L, EW1H, EW1L, PSL, 4096, 1024, 2048, 16);
  vq_ksum<4><<<(int)(N_H1 / 4 / 256), 256, 0, stream>>>(
      PSL, eb1, H1H, H1L, (int)N_H1, 1024, 1.0f / (SA * SW), SA);
  // enc2: 128^2 2-phase
  vq_gemm<1, 1><<<(4096 / BM) * (512 / BN), 256, 0, stream>>>(
      H1H, H1L, EW2H, EW2L, eb2, H2H, H2L, 4096, 512, 1024, 1.0f / (SA * SW), SA);

  // ---- 3. VQ ----
  vq_tpose<<<BATCH * 64, 256, 0, stream>>>(H2H, H2L, FLH, FLL);
  // dist GEMM + fused per-tile argmin (G matrix eliminated)
  vq_gemm<1, 5><<<(16384 / BM) * (512 / BN), 256, 0, stream>>>(
      FLH, FLL, CBH, CBL, CBN, CANDV, CANDI, 16384, 512, 128, 1.0f / (SA * SCB), 0.f);
  vq_argmin4<<<(BATCH * LDIM) / 256, 256, 0, stream>>>(CANDV, CANDI, INDS);
  vq_gather_loss<<<8448, 256, 0, stream>>>(cb, INDS, Z0, FLH, FLL, PART);
  vq_loss_final<<<1, 256, 0, stream>>>(PART, out + 33554432);

  // ---- 4. decoder ----
  vq_gemm<0, 2><<<(4096 / BM) * (1024 / BN), 256, 0, stream>>>(
      Z0, nullptr, DW0, nullptr, db0, ZH1, nullptr, 4096, 1024, 512, 1.0f / (SQ * SW), SQ);
  // dec1: 256x128 merged 2-phase, grid 256, NTloc = 1024/64 = 16
  vq_gemm8<0, 2, 4, 2, 4><<<dim3(256, 1), 512, 0, stream>>>(
      ZH1, nullptr, DW1, nullptr, db1, ZH2, nullptr, 4096, 2048, 1024, 16, 1.0f / (SQ * SW), SQ);
  // dec2: 256x256 8-phase, grid 256, NTloc = 2048/64 = 32 (writes out0 last)
  vq_gemm8<0, 3, 2, 4, 8><<<dim3(256, 1), 512, 0, stream>>>(
      ZH2, nullptr, DW2, nullptr, db2, out, nullptr, 4096, 4096, 2048, 32, 1.0f / (SQ * SW), 0.f);

  (void)in_sizes; (void)n_in; (void)out_size; (void)ws_size;
}